// Round 5
// baseline (104.389 us; speedup 1.0000x reference)
//
#include <hip/hip_runtime.h>

// LocallyConnected2D: out[b,p,f] = sum_k x_patch[b,p,k] * kernel[p,k,f] + bias[p,f]
// B=16, H=W=64, C=32, KH=KW=3, OH=OW=62, P=3844, F=64, fp32.
//
// Memory-bound on the 283 MB weight stream (read exactly once).
// R4: batch-split geometry. One wave per p; lane = (b4, fq): b4 = lane>>4
// owns batches 4*b4..4*b4+3, fq = lane&15 owns f-quad fq*4..+3.
//  - x reads per c4-step drop 16 -> 4 per wave (R0/R3 were bound by the
//    x-broadcast return pipe: 15p x 72steps x 16 reads x 12cy = 86us = the
//    measured 81us wall). Now ~11us, under the 45us weight-stream floor.
//  - waves 961 -> 3844 (~3.75/SIMD): 4x latency hiding. No LDS, no barrier.
//  - weight float4 loads: 16 fq-lanes cover 256B contiguous, broadcast
//    across the 4 b4-groups; traffic unchanged (each weight read once).
// Lessons: R1 = never make x addrs provably wave-uniform (scalarizes to
// s_load + lgkmcnt drains). R2 = no runtime-indexed acc arrays (scratch
// spill -> 911MB writes); all acc/xv indexing below is compile-time.

namespace {
constexpr int Hc = 64, Wc = 64, Cc = 32;
constexpr int OWc = 62;
constexpr int Pc = 62 * 62;      // 3844
constexpr int Fc = 64;
constexpr int KFc = 288 * 64;    // K*F per position
constexpr int XB = Hc * Wc * Cc; // per-batch x stride (floats)
constexpr int PPB = 4;           // p's per 256-thread block (1 per wave)
}

__global__ __launch_bounds__(256, 2)
void lc2d(const float* __restrict__ x, const float* __restrict__ kern,
          const float* __restrict__ bias, float* __restrict__ out)
{
    const int t    = threadIdx.x;
    const int lane = t & 63;
    const int wid  = t >> 6;
    const int fq   = lane & 15;
    const int f0   = fq << 2;
    const int b4   = lane >> 4;        // batch quad: batches 4*b4 .. 4*b4+3
    const int bb   = b4 << 2;

    const int p  = blockIdx.x * PPB + wid;   // grid is exactly P/4 blocks
    const int oh = p / OWc;
    const int ow = p - oh * OWc;

    const float* kbase = kern + (size_t)p * KFc + f0;
    // x base for this lane's first batch at patch origin (oh, ow), channel 0
    const float* xbase = x + (((size_t)bb * Hc + oh) * Wc + ow) * Cc;

    float4 acc0, acc1, acc2, acc3;
    const float4 bv = *(const float4*)(bias + (size_t)p * Fc + f0);
    acc0 = bv; acc1 = bv; acc2 = bv; acc3 = bv;

    #pragma unroll
    for (int kh = 0; kh < 3; ++kh) {
      #pragma unroll
      for (int kw = 0; kw < 3; ++kw) {
        const float* xk = xbase + ((size_t)kh * Wc + kw) * Cc;
        const float* kk = kbase + (size_t)((kh * 3 + kw) * 32) * Fc;
        #pragma unroll 2
        for (int c4 = 0; c4 < 8; ++c4) {
          const float4 kv0 = *(const float4*)(kk + (c4 * 4 + 0) * Fc);
          const float4 kv1 = *(const float4*)(kk + (c4 * 4 + 1) * Fc);
          const float4 kv2 = *(const float4*)(kk + (c4 * 4 + 2) * Fc);
          const float4 kv3 = *(const float4*)(kk + (c4 * 4 + 3) * Fc);
          const float4 xv0 = *(const float4*)(xk + (size_t)0 * XB + c4 * 4);
          const float4 xv1 = *(const float4*)(xk + (size_t)1 * XB + c4 * 4);
          const float4 xv2 = *(const float4*)(xk + (size_t)2 * XB + c4 * 4);
          const float4 xv3 = *(const float4*)(xk + (size_t)3 * XB + c4 * 4);
          acc0.x = fmaf(xv0.x, kv0.x, fmaf(xv0.y, kv1.x, fmaf(xv0.z, kv2.x, fmaf(xv0.w, kv3.x, acc0.x))));
          acc0.y = fmaf(xv0.x, kv0.y, fmaf(xv0.y, kv1.y, fmaf(xv0.z, kv2.y, fmaf(xv0.w, kv3.y, acc0.y))));
          acc0.z = fmaf(xv0.x, kv0.z, fmaf(xv0.y, kv1.z, fmaf(xv0.z, kv2.z, fmaf(xv0.w, kv3.z, acc0.z))));
          acc0.w = fmaf(xv0.x, kv0.w, fmaf(xv0.y, kv1.w, fmaf(xv0.z, kv2.w, fmaf(xv0.w, kv3.w, acc0.w))));
          acc1.x = fmaf(xv1.x, kv0.x, fmaf(xv1.y, kv1.x, fmaf(xv1.z, kv2.x, fmaf(xv1.w, kv3.x, acc1.x))));
          acc1.y = fmaf(xv1.x, kv0.y, fmaf(xv1.y, kv1.y, fmaf(xv1.z, kv2.y, fmaf(xv1.w, kv3.y, acc1.y))));
          acc1.z = fmaf(xv1.x, kv0.z, fmaf(xv1.y, kv1.z, fmaf(xv1.z, kv2.z, fmaf(xv1.w, kv3.z, acc1.z))));
          acc1.w = fmaf(xv1.x, kv0.w, fmaf(xv1.y, kv1.w, fmaf(xv1.z, kv2.w, fmaf(xv1.w, kv3.w, acc1.w))));
          acc2.x = fmaf(xv2.x, kv0.x, fmaf(xv2.y, kv1.x, fmaf(xv2.z, kv2.x, fmaf(xv2.w, kv3.x, acc2.x))));
          acc2.y = fmaf(xv2.x, kv0.y, fmaf(xv2.y, kv1.y, fmaf(xv2.z, kv2.y, fmaf(xv2.w, kv3.y, acc2.y))));
          acc2.z = fmaf(xv2.x, kv0.z, fmaf(xv2.y, kv1.z, fmaf(xv2.z, kv2.z, fmaf(xv2.w, kv3.z, acc2.z))));
          acc2.w = fmaf(xv2.x, kv0.w, fmaf(xv2.y, kv1.w, fmaf(xv2.z, kv2.w, fmaf(xv2.w, kv3.w, acc2.w))));
          acc3.x = fmaf(xv3.x, kv0.x, fmaf(xv3.y, kv1.x, fmaf(xv3.z, kv2.x, fmaf(xv3.w, kv3.x, acc3.x))));
          acc3.y = fmaf(xv3.x, kv0.y, fmaf(xv3.y, kv1.y, fmaf(xv3.z, kv2.y, fmaf(xv3.w, kv3.y, acc3.y))));
          acc3.z = fmaf(xv3.x, kv0.z, fmaf(xv3.y, kv1.z, fmaf(xv3.z, kv2.z, fmaf(xv3.w, kv3.z, acc3.z))));
          acc3.w = fmaf(xv3.x, kv0.w, fmaf(xv3.y, kv1.w, fmaf(xv3.z, kv2.w, fmaf(xv3.w, kv3.w, acc3.w))));
        }
      }
    }

    float* ob = out + ((size_t)bb * Pc + p) * Fc + f0;
    *(float4*)(ob + (size_t)0 * (Pc * Fc)) = acc0;
    *(float4*)(ob + (size_t)1 * (Pc * Fc)) = acc1;
    *(float4*)(ob + (size_t)2 * (Pc * Fc)) = acc2;
    *(float4*)(ob + (size_t)3 * (Pc * Fc)) = acc3;
}

extern "C" void kernel_launch(void* const* d_in, const int* in_sizes, int n_in,
                              void* d_out, int out_size, void* d_ws, size_t ws_size,
                              hipStream_t stream)
{
    const float* x    = (const float*)d_in[0];
    const float* kern = (const float*)d_in[1];
    const float* bias = (const float*)d_in[2];
    float* out = (float*)d_out;
    dim3 grid(Pc / PPB);   // 3844/4 = 961 blocks, exact
    lc2d<<<grid, 256, 0, stream>>>(x, kern, bias, out);
}